// Round 4
// baseline (117.252 us; speedup 1.0000x reference)
//
#include <hip/hip_runtime.h>
#include <hip/hip_bf16.h>
#include <math.h>

#define B_ 256
#define D_ 512
#define C_ 100000
#define BN 32
#define NBLK 256
#define NPAN (C_ / BN)   // 3125

#define SCALE_  64.0f
#define ALPHA_  1.2f
// THRESH = cos(pi - 0.5), MM = sin(pi - 0.5) * 0.5
#define THRESH_ (-0.8775825618903728f)
#define MM_     (0.23971276930210156f)
#define COSM_   (0.8775825618903728f)   // cos(0.5)
#define SINM_   (0.4794255386042030f)   // sin(0.5)

typedef __bf16 bf16x8 __attribute__((ext_vector_type(8)));
typedef __bf16 bf16x4 __attribute__((ext_vector_type(4)));
typedef float  f32x4  __attribute__((ext_vector_type(4)));

// ---------------------------------------------------------------------------
// prep: normalize input rows -> bf16 in MFMA-A-frag-linear layout
// (1 KiB tiles; tile_idx = rowtile*16 + ktile; lane holds row (b&15),
// k-group l&3). Also a_lb + canonical labels.
// ---------------------------------------------------------------------------
__global__ void prep_kernel(const float* __restrict__ inp,
                            const int* __restrict__ lab_raw,
                            const float* __restrict__ weight,
                            __bf16* __restrict__ xnf,
                            float* __restrict__ a_lb,
                            int* __restrict__ lab32) {
    const int b = blockIdx.x;
    const int l = threadIdx.x;   // 0..63  (covers cols l*8 .. l*8+7)

    const bool is64 = (lab_raw[1] == 0) & (lab_raw[3] == 0) & (lab_raw[5] == 0) &
                      (lab_raw[7] == 0) & (lab_raw[9] == 0) & (lab_raw[11] == 0) &
                      (lab_raw[13] == 0) & (lab_raw[15] == 0);
    const int lab = is64 ? lab_raw[2 * b] : lab_raw[b];

    const float* ip = inp + b * D_ + l * 8;
    f32x4 v0 = *(const f32x4*)ip;
    f32x4 v1 = *(const f32x4*)(ip + 4);
    float ss = v0.x * v0.x + v0.y * v0.y + v0.z * v0.z + v0.w * v0.w +
               v1.x * v1.x + v1.y * v1.y + v1.z * v1.z + v1.w * v1.w;
#pragma unroll
    for (int m = 1; m < 64; m <<= 1) ss += __shfl_xor(ss, m);
    const float ninv = 1.0f / fmaxf(sqrtf(ss), 1e-12f);

    float xf[8] = {v0.x * ninv, v0.y * ninv, v0.z * ninv, v0.w * ninv,
                   v1.x * ninv, v1.y * ninv, v1.z * ninv, v1.w * ninv};
    bf16x8 xv;
#pragma unroll
    for (int i = 0; i < 8; ++i) xv[i] = (__bf16)xf[i];

    const int tile_idx = (b >> 4) * 16 + (l >> 2);
    const int lf = (b & 15) + ((l & 3) << 4);
    *(bf16x8*)((char*)xnf + tile_idx * 1024 + lf * 16) = xv;

    const float* wp = weight + (size_t)lab * D_ + l * 8;
    f32x4 w0 = *(const f32x4*)wp;
    f32x4 w1 = *(const f32x4*)(wp + 4);
    float wss = w0.x * w0.x + w0.y * w0.y + w0.z * w0.z + w0.w * w0.w +
                w1.x * w1.x + w1.y * w1.y + w1.z * w1.z + w1.w * w1.w;
    float dp = xf[0] * w0.x + xf[1] * w0.y + xf[2] * w0.z + xf[3] * w0.w +
               xf[4] * w1.x + xf[5] * w1.y + xf[6] * w1.z + xf[7] * w1.w;
#pragma unroll
    for (int m = 1; m < 64; m <<= 1) {
        wss += __shfl_xor(wss, m);
        dp  += __shfl_xor(dp, m);
    }
    if (l == 0) {
        const float cos_lb = dp / fmaxf(sqrtf(wss), 1e-12f);
        const float ccl = fminf(fmaxf(cos_lb, -1.0f), 1.0f);
        const float s = sqrtf(fmaxf(0.0f, 1.0f - ccl * ccl));
        const float a1 = ccl * COSM_ - s * SINM_;
        a_lb[b] = (cos_lb > THRESH_) ? a1 : (cos_lb - MM_);
        lab32[b] = lab;
    }
}

// ---------------------------------------------------------------------------
// Persistent GEMM. 256 blocks x 512 threads (8 waves), 1 block/CU.
// Wave w holds A rows w*32..+31 x K=512 ENTIRELY IN REGISTERS (32 frags).
// Block loops over panels bid + it*256 (BN=32 cols). Per panel:
//   sweep (ds_read + MFMA only) -> epilogue -> stage W(p+1) regs->LDS
//   -> issue W(p+2) global loads -> one barrier.
// W loads have a full panel period to complete: continuous HBM streaming.
// ---------------------------------------------------------------------------
__device__ __forceinline__ void stage_panel(const f32x4* wv, char* wbuf,
                                            float* wsq, int w, int lane) {
    float ss = 0.0f;
#pragma unroll
    for (int i = 0; i < 8; ++i) {
        f32x4 v = wv[i];
        ss += v.x * v.x + v.y * v.y + v.z * v.z + v.w * v.w;
        bf16x4 h;
        h[0] = (__bf16)v.x; h[1] = (__bf16)v.y;
        h[2] = (__bf16)v.z; h[3] = (__bf16)v.w;
        const int row = w * 4 + (i >> 1);
        int off = (row << 10) + ((i & 1) << 9) + lane * 8;
        off ^= (row & 7) << 4;
        *(bf16x4*)(wbuf + off) = h;
        if (i & 1) {
#pragma unroll
            for (int msk = 1; msk < 64; msk <<= 1) ss += __shfl_xor(ss, msk);
            if (lane == 0) wsq[row] = ss;
            ss = 0.0f;
        }
    }
}

__global__ __launch_bounds__(512, 2)
void gemm_kernel(const __bf16* __restrict__ xnf,
                 const float* __restrict__ weight,
                 const float* __restrict__ a_lb,
                 const int* __restrict__ lab32,
                 float* __restrict__ out) {
    __shared__ __align__(16) char wT[2][BN * D_ * 2];   // 2 x 32 KiB
    __shared__ float wssq[2][BN];

    const int tid  = threadIdx.x;
    const int lane = tid & 63;
    const int w    = tid >> 6;      // 0..7
    const int bid  = blockIdx.x;
    const int npan = (NPAN - bid + NBLK - 1) / NBLK;   // 12 or 13

    // issue W(panel 0) first (HBM latency)
    f32x4 wv[8];
    {
        const float* wp = weight + (size_t)(bid * BN + w * 4) * D_;
#pragma unroll
        for (int i = 0; i < 8; ++i)
            wv[i] = *(const f32x4*)(wp + (i >> 1) * D_ + (i & 1) * 256 + lane * 4);
    }

    // A-frags: rows w*32..+31, all K (L2-resident xnf), 128 VGPR
    bf16x8 af[2][16];
#pragma unroll
    for (int m = 0; m < 2; ++m)
#pragma unroll
        for (int kt = 0; kt < 16; ++kt)
            af[m][kt] = *(const bf16x8*)((const char*)xnf +
                          (((2 * w + m) * 16 + kt) << 10) + lane * 16);

    // per-row epilogue constants (panel-invariant)
    float al_r[8];
    int   lb_r[8];
    const int rb0 = w * 32 + ((lane >> 4) << 2);
#pragma unroll
    for (int m = 0; m < 2; ++m)
#pragma unroll
        for (int j = 0; j < 4; ++j) {
            al_r[m * 4 + j] = a_lb[rb0 + m * 16 + j];
            lb_r[m * 4 + j] = lab32[rb0 + m * 16 + j];
        }

    // prologue: stage panel 0, issue W(panel 1)
    stage_panel(wv, wT[0], wssq[0], w, lane);
    if (npan > 1) {
        const float* wp = weight + (size_t)((bid + NBLK) * BN + w * 4) * D_;
#pragma unroll
        for (int i = 0; i < 8; ++i)
            wv[i] = *(const f32x4*)(wp + (i >> 1) * D_ + (i & 1) * 256 + lane * 4);
    }
    __syncthreads();

    for (int it = 0; it < npan; ++it) {
        const int n0 = (bid + it * NBLK) * BN;
        const char* wb = wT[it & 1];

        // ---- sweep: ds_read + MFMA only, bfr double-buffered
        f32x4 acc[2][2] = {};
        bf16x8 bfr[2][2];
#pragma unroll
        for (int n = 0; n < 2; ++n) {
            const int row = n * 16 + (lane & 15);
            int off = (row << 10) + ((lane >> 4) << 4);
            off ^= (row & 7) << 4;
            bfr[0][n] = *(const bf16x8*)(wb + off);
        }
#pragma unroll
        for (int kt = 0; kt < 16; ++kt) {
            const int cb = kt & 1;
            if (kt < 15) {
#pragma unroll
                for (int n = 0; n < 2; ++n) {
                    const int row = n * 16 + (lane & 15);
                    int off = (row << 10) + ((kt + 1) << 6) + ((lane >> 4) << 4);
                    off ^= (row & 7) << 4;
                    bfr[cb ^ 1][n] = *(const bf16x8*)(wb + off);
                }
            }
#pragma unroll
            for (int m = 0; m < 2; ++m)
#pragma unroll
                for (int n = 0; n < 2; ++n)
                    acc[m][n] = __builtin_amdgcn_mfma_f32_16x16x32_bf16(
                        af[m][kt], bfr[cb][n], acc[m][n], 0, 0, 0);
        }

        // ---- epilogue
#pragma unroll
        for (int n = 0; n < 2; ++n) {
            const int ln = n * 16 + (lane & 15);
            const int c = n0 + ln;
            const float winv = 1.0f / fmaxf(sqrtf(wssq[it & 1][ln]), 1e-12f);
#pragma unroll
            for (int m = 0; m < 2; ++m)
#pragma unroll
                for (int j = 0; j < 4; ++j) {
                    const float al = al_r[m * 4 + j];
                    const float cosv = acc[m][n][j] * winv;
                    const float d = cosv - al;
                    const float t = ALPHA_ * __expf(-0.5f * d * d);  // SIGMA=2
                    const float o = (c == lb_r[m * 4 + j]) ? al
                                                           : (t * cosv + t - 1.0f);
                    out[(size_t)(rb0 + m * 16 + j) * C_ + c] = SCALE_ * o;
                }
        }

        // ---- stage next panel from regs, then issue next-next loads
        if (it + 1 < npan) {
            stage_panel(wv, wT[(it + 1) & 1], wssq[(it + 1) & 1], w, lane);
            if (it + 2 < npan) {
                const float* wp = weight +
                    (size_t)((bid + (it + 2) * NBLK) * BN + w * 4) * D_;
#pragma unroll
                for (int i = 0; i < 8; ++i)
                    wv[i] = *(const f32x4*)(wp + (i >> 1) * D_ + (i & 1) * 256 + lane * 4);
            }
        }
        __syncthreads();
    }
}

extern "C" void kernel_launch(void* const* d_in, const int* in_sizes, int n_in,
                              void* d_out, int out_size, void* d_ws, size_t ws_size,
                              hipStream_t stream) {
    const float* inp = (const float*)d_in[0];
    const int*   lab = (const int*)d_in[1];
    const float* w   = (const float*)d_in[2];
    float* out = (float*)d_out;

    char* ws = (char*)d_ws;
    __bf16* xnf  = (__bf16*)ws;                       // 262144 B
    float*  a_lb = (float*)(ws + 262144);             // 1 KiB
    int*    l32  = (int*)(ws + 262144 + 1024);        // 1 KiB

    prep_kernel<<<B_, 64, 0, stream>>>(inp, lab, w, xnf, a_lb, l32);
    gemm_kernel<<<NBLK, 512, 0, stream>>>(xnf, w, a_lb, l32, out);
}